// Round 12
// baseline (298.949 us; speedup 1.0000x reference)
//
#include <hip/hip_runtime.h>
#include <hip/hip_bf16.h>
#include <math.h>

typedef unsigned short u16;
typedef unsigned int   u32;
typedef short bf16x8 __attribute__((ext_vector_type(8)));
typedef float f32x4  __attribute__((ext_vector_type(4)));
typedef float f32x16 __attribute__((ext_vector_type(16)));
typedef u32   u32x4  __attribute__((ext_vector_type(4)));
typedef u32   u32x2  __attribute__((ext_vector_type(2)));

#define B_   4
#define S_   2048
#define D_   1024
#define H_   16
#define HD_  64
#define M_   (B_*S_)   // 8192 rows

static __device__ __forceinline__ u16 f2bf(float f) {
  __hip_bfloat16 h = __float2bfloat16(f);
  return *reinterpret_cast<u16*>(&h);
}
static __device__ __forceinline__ u32 pack_bf(float lo, float hi) {
  return (u32)f2bf(lo) | ((u32)f2bf(hi) << 16);
}
// truncation pack: [hi.bf16 : lo.bf16] in one v_perm_b32
static __device__ __forceinline__ u32 pack_bf_trunc(float lo, float hi) {
  return __builtin_amdgcn_perm(__float_as_uint(hi), __float_as_uint(lo), 0x07060302u);
}
static __device__ __forceinline__ f32x16 zero16() {
  f32x16 z;
#pragma unroll
  for (int i = 0; i < 16; ++i) z[i] = 0.f;
  return z;
}

// async global->LDS, 16B per lane; lds base must be wave-uniform (lane*16 auto-added)
typedef __attribute__((address_space(1))) const u32* gas_t;
typedef __attribute__((address_space(3))) u32* las_t;
static __device__ __forceinline__ void g2l16(const void* g, void* l) {
  __builtin_amdgcn_global_load_lds((gas_t)g, (las_t)l, 16, 0, 0);
}

// ---------------- fused cast fp32 -> bf16 (x + 4 weights in one launch) ------
// R12: 8 elems/thread — two float4 loads, one 16B u32x4 store (was 8B uint2).
// Halves instruction + block count (12288 -> 6144); full-width stores.
__global__ __launch_bounds__(256) void cast_all(const float* __restrict__ x,
                                                const float* __restrict__ Wq,
                                                const float* __restrict__ Wk,
                                                const float* __restrict__ Wv,
                                                const float* __restrict__ Wo,
                                                u16* __restrict__ xb,
                                                u16* __restrict__ Wqb,
                                                u16* __restrict__ Wkb,
                                                u16* __restrict__ Wvb,
                                                u16* __restrict__ Wob) {
  int bid = blockIdx.x;
  const float* src;
  u16* dst;
  int off;
  if (bid < 4096) {                   // x: 8M elems, 2048/block
    src = x; dst = xb; off = bid;
  } else {                            // weights: 1M elems each, 512 blocks each
    int t = bid - 4096;
    int w = t >> 9;
    off   = t & 511;
    src = w == 0 ? Wq : w == 1 ? Wk : w == 2 ? Wv : Wo;
    dst = w == 0 ? Wqb : w == 1 ? Wkb : w == 2 ? Wvb : Wob;
  }
  int i = (off * 256 + threadIdx.x) * 8;
  float4 v0 = *reinterpret_cast<const float4*>(src + i);
  float4 v1 = *reinterpret_cast<const float4*>(src + i + 4);
  u32x4 o;
  o[0] = pack_bf(v0.x, v0.y);
  o[1] = pack_bf(v0.z, v0.w);
  o[2] = pack_bf(v1.x, v1.y);
  o[3] = pack_bf(v1.z, v1.w);
  *reinterpret_cast<u32x4*>(dst + i) = o;
}

// ---------------- fused QKV GEMM: 3x [8192x1024]x[1024x1024]^T ----------------
// Verified-best structure (R3/R7/R10/R11): single-buffer 16KB LDS, 2-barrier
// K-loop, strength-reduced staging pointers, which-major XCD chunking
// (per-XCD: 2MB A-chunk resident across all 3 which-phases + 2MB W-slice
// = 4MB = L2; A read from HBM once). dbuf retested twice (R2, R8) —
// regresses at 128^2: multi-block implicit overlap IS the pipeline.
__global__ __launch_bounds__(256) void gemm_qkv(const u16* __restrict__ A,
                                                const u16* __restrict__ Wq,
                                                const u16* __restrict__ Wk,
                                                const u16* __restrict__ Wv,
                                                const float* __restrict__ bq,
                                                const float* __restrict__ bk,
                                                const float* __restrict__ bv,
                                                u16* __restrict__ Qo,
                                                u16* __restrict__ Ko,
                                                u16* __restrict__ Vo) {
  const int tid  = threadIdx.x;
  const int lane = tid & 63;
  const int wave = tid >> 6;
  const int m16  = lane & 15;
  const int quad = lane >> 4;
  const int wm   = wave & 1;
  const int wn   = wave >> 1;

  // which-major bijective XCD chunking (nwg=1536, 1536%8==0)
  const int bid  = blockIdx.x;
  const int xcd  = bid & 7;
  const int j    = bid >> 3;        // [0,192)
  const int which = j >> 6;         // {0,1,2}
  const int jj   = j & 63;
  const int m0   = (xcd * 8 + (jj >> 3)) * 128;
  const int n0   = (jj & 7) * 128;

  const u16* W = which == 0 ? Wq : which == 1 ? Wk : Wv;
  const float* bias = which == 0 ? bq : which == 1 ? bk : bv;

  __shared__ __align__(16) u16 As[128 * 32];
  __shared__ __align__(16) u16 Bs[128 * 32];

  f32x4 acc[4][4];
#pragma unroll
  for (int i = 0; i < 4; ++i)
#pragma unroll
    for (int j2 = 0; j2 < 4; ++j2) acc[i][j2] = (f32x4){0.f, 0.f, 0.f, 0.f};

  // strength-reduced staging pointers: slot e holds row=e>>2, c8=(e&3)*8
  const int eA = (wave << 6) + lane;         // i=0 slot
  const int eB = 256 + (wave << 6) + lane;   // i=1 slot
  const int r0_ = eA >> 2, c0_ = (eA & 3) * 8;
  const int r1_ = eB >> 2, c1_ = (eB & 3) * 8;
  const u16* pa0 = A + (size_t)(m0 + r0_) * 1024 + c0_;
  const u16* pa1 = A + (size_t)(m0 + r1_) * 1024 + c1_;
  const u16* pw0 = W + (size_t)(n0 + r0_) * 1024 + c0_;
  const u16* pw1 = W + (size_t)(n0 + r1_) * 1024 + c1_;
  u16* lA0 = &As[((wave << 6)) * 8];
  u16* lA1 = &As[((wave << 6) + 256) * 8];
  u16* lB0 = &Bs[((wave << 6)) * 8];
  u16* lB1 = &Bs[((wave << 6) + 256) * 8];

  for (int t = 0; t < 32; ++t) {
    g2l16(pa0, lA0);
    g2l16(pw0, lB0);
    g2l16(pa1, lA1);
    g2l16(pw1, lB1);
    pa0 += 32; pa1 += 32; pw0 += 32; pw1 += 32;
    __syncthreads();   // drains stage (compiler emits vmcnt(0) before barrier)

    bf16x8 af[4], bfr[4];
#pragma unroll
    for (int mt = 0; mt < 4; ++mt)
      af[mt] = *reinterpret_cast<const bf16x8*>(&As[(wm * 64 + mt * 16 + m16) * 32 + quad * 8]);
#pragma unroll
    for (int nt = 0; nt < 4; ++nt)
      bfr[nt] = *reinterpret_cast<const bf16x8*>(&Bs[(wn * 64 + nt * 16 + m16) * 32 + quad * 8]);

#pragma unroll
    for (int mt = 0; mt < 4; ++mt)
#pragma unroll
      for (int nt = 0; nt < 4; ++nt)
        acc[mt][nt] = __builtin_amdgcn_mfma_f32_16x16x32_bf16(af[mt], bfr[nt], acc[mt][nt], 0, 0, 0);
    __syncthreads();
  }

  const float scale = which == 0 ? 0.125f * 1.44269504f : 1.0f;
  u16* ob = which == 0 ? Qo : which == 1 ? Ko : Vo;
#pragma unroll
  for (int mt = 0; mt < 4; ++mt) {
#pragma unroll
    for (int nt = 0; nt < 4; ++nt) {
      int col = n0 + wn * 64 + nt * 16 + m16;
      float bi = bias[col];
      int row0 = m0 + wm * 64 + mt * 16 + quad * 4;
      int b = row0 >> 11, s = row0 & 2047;
      int h = col >> 6,  d = col & 63;
      float v[4];
#pragma unroll
      for (int r = 0; r < 4; ++r) v[r] = (acc[mt][nt][r] + bi) * scale;
      if (which < 2) {
#pragma unroll
        for (int r = 0; r < 4; ++r)
          ob[(size_t)((b * H_ + h) * S_ + s + r) * HD_ + d] = f2bf(v[r]);
      } else {
        // V^T store: 4 consecutive s -> one 8B store
        uint2 w;
        w.x = pack_bf(v[0], v[1]);
        w.y = pack_bf(v[2], v[3]);
        *reinterpret_cast<uint2*>(&ob[(size_t)((b * H_ + h) * HD_ + d) * S_ + s]) = w;
      }
    }
  }
}

// ---------------- O-projection GEMM (fp32 out), single-buffer, XCD chunked ---
// fp32 output (R7/R10/R11): full 64B-line stores. R9's bf16 output halved
// the store segment to 32B -> partial-line HBM writes cost more than the
// 16MB of traffic saved.
__global__ __launch_bounds__(256) void gemm_bt(const u16* __restrict__ A,
                                               const u16* __restrict__ W,
                                               const float* __restrict__ bias,
                                               float* __restrict__ out) {
  const int tid  = threadIdx.x;
  const int lane = tid & 63;
  const int wave = tid >> 6;
  const int m16  = lane & 15;
  const int quad = lane >> 4;
  const int wm   = wave & 1;
  const int wn   = wave >> 1;

  // bijective XCD chunking: nwg=512; per-XCD 8 m-panels x 8 n-panels (4MB)
  const int bid = blockIdx.x;
  const int xcd = bid & 7;
  const int j   = bid >> 3;    // [0,64)
  const int m0  = (xcd * 8 + (j >> 3)) * 128;
  const int n0  = (j & 7) * 128;

  __shared__ __align__(16) u16 As[128 * 32];
  __shared__ __align__(16) u16 Bs[128 * 32];

  f32x4 acc[4][4];
#pragma unroll
  for (int i = 0; i < 4; ++i)
#pragma unroll
    for (int j2 = 0; j2 < 4; ++j2) acc[i][j2] = (f32x4){0.f, 0.f, 0.f, 0.f};

  const int eA = (wave << 6) + lane;
  const int eB = 256 + (wave << 6) + lane;
  const int r0_ = eA >> 2, c0_ = (eA & 3) * 8;
  const int r1_ = eB >> 2, c1_ = (eB & 3) * 8;
  const u16* pa0 = A + (size_t)(m0 + r0_) * 1024 + c0_;
  const u16* pa1 = A + (size_t)(m0 + r1_) * 1024 + c1_;
  const u16* pw0 = W + (size_t)(n0 + r0_) * 1024 + c0_;
  const u16* pw1 = W + (size_t)(n0 + r1_) * 1024 + c1_;
  u16* lA0 = &As[((wave << 6)) * 8];
  u16* lA1 = &As[((wave << 6) + 256) * 8];
  u16* lB0 = &Bs[((wave << 6)) * 8];
  u16* lB1 = &Bs[((wave << 6) + 256) * 8];

  for (int t = 0; t < 32; ++t) {
    g2l16(pa0, lA0);
    g2l16(pw0, lB0);
    g2l16(pa1, lA1);
    g2l16(pw1, lB1);
    pa0 += 32; pa1 += 32; pw0 += 32; pw1 += 32;
    __syncthreads();

    bf16x8 af[4], bfr[4];
#pragma unroll
    for (int mt = 0; mt < 4; ++mt)
      af[mt] = *reinterpret_cast<const bf16x8*>(&As[(wm * 64 + mt * 16 + m16) * 32 + quad * 8]);
#pragma unroll
    for (int nt = 0; nt < 4; ++nt)
      bfr[nt] = *reinterpret_cast<const bf16x8*>(&Bs[(wn * 64 + nt * 16 + m16) * 32 + quad * 8]);

#pragma unroll
    for (int mt = 0; mt < 4; ++mt)
#pragma unroll
      for (int nt = 0; nt < 4; ++nt)
        acc[mt][nt] = __builtin_amdgcn_mfma_f32_16x16x32_bf16(af[mt], bfr[nt], acc[mt][nt], 0, 0, 0);
    __syncthreads();
  }

#pragma unroll
  for (int mt = 0; mt < 4; ++mt) {
#pragma unroll
    for (int nt = 0; nt < 4; ++nt) {
      int col = n0 + wn * 64 + nt * 16 + m16;
      float bi = bias[col];
#pragma unroll
      for (int r = 0; r < 4; ++r) {
        int row = m0 + wm * 64 + mt * 16 + quad * 4 + r;
        out[(size_t)row * 1024 + col] = acc[mt][nt][r] + bi;
      }
    }
  }
}

// ---------------- flash attention, 32x32 MFMA ----------------
// Best measured attn (83.8-85.4us across R9/R10/R11, stable): R1 indexing
// (no XCD swizzle — duration-neutral-to-negative despite FETCH 139->25MB),
// plain epilogue stores (nt-stores caused 4-5x write amplification),
// strength-reduced prefetch pointers, dbuf 1-barrier loop, permlane32_swap,
// setprio, VALU lsum denominator. Occupancy is LDS-capped at 4 blocks/CU
// which the 1024-block grid exactly fills.
__global__ __launch_bounds__(256, 4) void attn_kernel(const u16* __restrict__ Q,
                                                      const u16* __restrict__ K,
                                                      const u16* __restrict__ Vt,
                                                      u16* __restrict__ out) {
  const int tid  = threadIdx.x;
  const int lane = tid & 63;
  const int wave = tid >> 6;
  const int r32  = lane & 31;
  const int h32  = lane >> 5;
  const int bh   = blockIdx.y;
  const int q0   = blockIdx.x * 128 + wave * 32;

  __shared__ __align__(16) u16 Ks[2][64 * 72];   // [buf][key][d], stride 72
  __shared__ __align__(16) u16 Vs[2][64 * 72];   // [buf][d][key]

  const u16* kbase = K  + (size_t)bh * S_ * HD_;
  const u16* vbase = Vt + (size_t)bh * HD_ * S_;
  const int e  = tid;          // staging slot 0
  const int e2 = tid + 256;    // staging slot 1
  const int row_a = e >> 3,  c8_a = (e & 7) * 8;
  const int row_b = e2 >> 3, c8_b = (e2 & 7) * 8;

  // Q B-frags: B[k=d][n=qrow]
  bf16x8 qf[4];
  {
    const u16* qbase = Q + (size_t)(bh * S_ + q0 + r32) * HD_ + h32 * 8;
#pragma unroll
    for (int dc = 0; dc < 4; ++dc)
      qf[dc] = *reinterpret_cast<const bf16x8*>(qbase + dc * 16);
  }

  f32x16 acc[2];   // O^T accum [dt], row=d col=qrow
#pragma unroll
  for (int dt = 0; dt < 2; ++dt) acc[dt] = zero16();
  float lsum = 0.f;

  // strength-reduced prefetch pointers
  const u16* pkp0 = kbase + (size_t)row_a * HD_ + c8_a;
  const u16* pkp1 = kbase + (size_t)row_b * HD_ + c8_b;
  const u16* pvp0 = vbase + (size_t)row_a * S_ + c8_a;
  const u16* pvp1 = vbase + (size_t)row_b * S_ + c8_b;

  // prefetch tile 0
  uint4 kr0 = *reinterpret_cast<const uint4*>(pkp0);
  uint4 kr1 = *reinterpret_cast<const uint4*>(pkp1);
  uint4 vr0 = *reinterpret_cast<const uint4*>(pvp0);
  uint4 vr1 = *reinterpret_cast<const uint4*>(pvp1);

  const int NT = S_ / 64;
  for (int kt = 0; kt < NT; ++kt) {
    u16* ks = Ks[kt & 1];
    u16* vs = Vs[kt & 1];
    // write prefetched tile to LDS (current buffer)
    *reinterpret_cast<uint4*>(&ks[row_a * 72 + c8_a]) = kr0;
    *reinterpret_cast<uint4*>(&ks[row_b * 72 + c8_b]) = kr1;
    *reinterpret_cast<uint4*>(&vs[row_a * 72 + c8_a]) = vr0;
    *reinterpret_cast<uint4*>(&vs[row_b * 72 + c8_b]) = vr1;
    __syncthreads();

    // issue next tile's loads (last iter reads slightly OOB into adjacent
    // ws regions; values discarded)
    pkp0 += 64 * HD_; pkp1 += 64 * HD_; pvp0 += 64; pvp1 += 64;
    kr0 = *reinterpret_cast<const uint4*>(pkp0);
    kr1 = *reinterpret_cast<const uint4*>(pkp1);
    vr0 = *reinterpret_cast<const uint4*>(pvp0);
    vr1 = *reinterpret_cast<const uint4*>(pvp1);

    // S^T tiles (two 32-key tiles x 32 qrows)
    f32x16 sc[2];
    __builtin_amdgcn_s_setprio(1);
#pragma unroll
    for (int nt = 0; nt < 2; ++nt) {
      sc[nt] = zero16();
#pragma unroll
      for (int dc = 0; dc < 4; ++dc) {
        bf16x8 kf = *reinterpret_cast<const bf16x8*>(&ks[(nt * 32 + r32) * 72 + dc * 16 + h32 * 8]);
        sc[nt] = __builtin_amdgcn_mfma_f32_32x32x16_bf16(kf, qf[dc], sc[nt], 0, 0, 0);
      }
    }
    __builtin_amdgcn_s_setprio(0);

    // fixed-max softmax: p = 2^score; truncation-pack pairs to bf16x2
    u32 pk[2][8];
    float ps0 = 0.f, ps1 = 0.f;
#pragma unroll
    for (int nt = 0; nt < 2; ++nt)
#pragma unroll
      for (int i = 0; i < 8; ++i) {
        float p0 = __builtin_amdgcn_exp2f(sc[nt][2 * i]);
        float p1 = __builtin_amdgcn_exp2f(sc[nt][2 * i + 1]);
        ps0 += p0;
        ps1 += p1;
        pk[nt][i] = pack_bf_trunc(p0, p1);
      }
    lsum += ps0 + ps1;

    // PV: assemble P^T B-frag per 16-key chunk via permlane32_swap,
    // accumulate O^T = V^T . P^T
    __builtin_amdgcn_s_setprio(1);
#pragma unroll
    for (int nt = 0; nt < 2; ++nt) {
#pragma unroll
      for (int kc2 = 0; kc2 < 2; ++kc2) {
        u32x2 r0 = __builtin_amdgcn_permlane32_swap(pk[nt][4 * kc2 + 0], pk[nt][4 * kc2 + 2], false, false);
        u32x2 r1 = __builtin_amdgcn_permlane32_swap(pk[nt][4 * kc2 + 1], pk[nt][4 * kc2 + 3], false, false);
        u32x4 bw;
        bw[0] = r0[0];
        bw[1] = r1[0];
        bw[2] = r0[1];
        bw[3] = r1[1];
        bf16x8 pfrag = *reinterpret_cast<bf16x8*>(&bw);
        const int kc = nt * 2 + kc2;
#pragma unroll
        for (int dt = 0; dt < 2; ++dt) {
          bf16x8 vf = *reinterpret_cast<const bf16x8*>(&vs[(dt * 32 + r32) * 72 + kc * 16 + h32 * 8]);
          acc[dt] = __builtin_amdgcn_mfma_f32_32x32x16_bf16(vf, pfrag, acc[dt], 0, 0, 0);
        }
      }
    }
    __builtin_amdgcn_s_setprio(0);
    // no second barrier: double-buffered LDS makes next-iter writes safe
  }

  // epilogue: O^T regs -> out[b, s, h*64+d]; d = dt*32 + 8g + 4*h32 + (0..3)
  const int b = bh >> 4, hh = bh & 15;
  float lt  = lsum + __shfl_xor(lsum, 32);
  float inv = 1.f / lt;
  int srow = q0 + r32;
  u16* orow = out + (size_t)(b * S_ + srow) * D_ + hh * HD_;
#pragma unroll
  for (int dt = 0; dt < 2; ++dt) {
#pragma unroll
    for (int g = 0; g < 4; ++g) {
      uint2 w;
      w.x = pack_bf(acc[dt][4 * g + 0] * inv, acc[dt][4 * g + 1] * inv);
      w.y = pack_bf(acc[dt][4 * g + 2] * inv, acc[dt][4 * g + 3] * inv);
      *reinterpret_cast<uint2*>(orow + dt * 32 + 8 * g + 4 * h32) = w;
    }
  }
}

// ---------------- layernorm: wave-per-row, no LDS, no barrier ----------------
// One 64-lane wave owns a full 1024-col row (16 elems/lane as 4x float4);
// reduction is pure shfl_xor. No __syncthreads, no LDS round-trip.
__global__ __launch_bounds__(256) void ln_kernel(const float* __restrict__ X,
                                                 const float* __restrict__ w,
                                                 const float* __restrict__ b,
                                                 float* __restrict__ out) {
  const int wave = threadIdx.x >> 6;
  const int lane = threadIdx.x & 63;
  const int row  = blockIdx.x * 4 + wave;
  const float* x = X + (size_t)row * 1024;

  float4 v[4];
  float s = 0.f, s2 = 0.f;
#pragma unroll
  for (int i = 0; i < 4; ++i) {
    v[i] = *reinterpret_cast<const float4*>(x + lane * 4 + i * 256);
    s  += (v[i].x + v[i].y) + (v[i].z + v[i].w);
    s2 += (v[i].x * v[i].x + v[i].y * v[i].y) + (v[i].z * v[i].z + v[i].w * v[i].w);
  }
#pragma unroll
  for (int off = 32; off; off >>= 1) {
    s  += __shfl_xor(s, off);
    s2 += __shfl_xor(s2, off);
  }
  float mu  = s * (1.f / 1024.f);
  float var = s2 * (1.f / 1024.f) - mu * mu;
  float inv = rsqrtf(var + 1e-5f);
  float* orow = out + (size_t)row * 1024;
#pragma unroll
  for (int i = 0; i < 4; ++i) {
    const int c = lane * 4 + i * 256;
    float4 wv = *reinterpret_cast<const float4*>(w + c);
    float4 bv = *reinterpret_cast<const float4*>(b + c);
    float4 o;
    o.x = (v[i].x - mu) * inv * wv.x + bv.x;
    o.y = (v[i].y - mu) * inv * wv.y + bv.y;
    o.z = (v[i].z - mu) * inv * wv.z + bv.z;
    o.w = (v[i].w - mu) * inv * wv.w + bv.w;
    *reinterpret_cast<float4*>(orow + c) = o;
  }
}

// ---------------- launch ----------------
extern "C" void kernel_launch(void* const* d_in, const int* in_sizes, int n_in,
                              void* d_out, int out_size, void* d_ws, size_t ws_size,
                              hipStream_t stream) {
  const float* x   = (const float*)d_in[0];
  const float* Wq  = (const float*)d_in[1];
  const float* bq  = (const float*)d_in[2];
  const float* Wk  = (const float*)d_in[3];
  const float* bk  = (const float*)d_in[4];
  const float* Wv  = (const float*)d_in[5];
  const float* bv  = (const float*)d_in[6];
  const float* Wo  = (const float*)d_in[7];
  const float* bo  = (const float*)d_in[8];
  const float* lnw = (const float*)d_in[9];
  const float* lnb = (const float*)d_in[10];

  const size_t MB = 1024ull * 1024ull;
  char* ws = (char*)d_ws;
  u16* xb  = (u16*)(ws + 0);        // 16 MB; later reused as attention output
  u16* Qb  = (u16*)(ws + 16 * MB);  // 16 MB
  u16* Kb  = (u16*)(ws + 32 * MB);  // 16 MB
  u16* Vtb = (u16*)(ws + 48 * MB);  // 16 MB
  u16* Wqb = (u16*)(ws + 64 * MB);  // 2 MB each
  u16* Wkb = (u16*)(ws + 66 * MB);
  u16* Wvb = (u16*)(ws + 68 * MB);
  u16* Wob = (u16*)(ws + 70 * MB);
  float* Of = (float*)(ws + 16 * MB); // 32 MB fp32, overlaps Qb/Kb (dead after attn)

  cast_all<<<4096 + 2048, 256, 0, stream>>>(x, Wq, Wk, Wv, Wo, xb, Wqb, Wkb, Wvb, Wob);

  gemm_qkv<<<(M_ / 128) * 3 * (D_ / 128), 256, 0, stream>>>(
      xb, Wqb, Wkb, Wvb, bq, bk, bv, Qb, Kb, Vtb);

  attn_kernel<<<dim3(S_ / 128, B_ * H_), 256, 0, stream>>>(Qb, Kb, Vtb, xb);

  gemm_bt<<<(M_ / 128) * (D_ / 128), 256, 0, stream>>>(xb, Wob, bo, Of);

  ln_kernel<<<M_ / 4, 256, 0, stream>>>(Of, lnw, lnb, (float*)d_out);
}

// Round 13
// 283.078 us; speedup vs baseline: 1.0561x; 1.0561x over previous
//
#include <hip/hip_runtime.h>
#include <hip/hip_bf16.h>
#include <math.h>

typedef unsigned short u16;
typedef unsigned int   u32;
typedef short bf16x8 __attribute__((ext_vector_type(8)));
typedef float f32x4  __attribute__((ext_vector_type(4)));
typedef float f32x16 __attribute__((ext_vector_type(16)));
typedef u32   u32x4  __attribute__((ext_vector_type(4)));
typedef u32   u32x2  __attribute__((ext_vector_type(2)));

#define B_   4
#define S_   2048
#define D_   1024
#define H_   16
#define HD_  64
#define M_   (B_*S_)   // 8192 rows

static __device__ __forceinline__ u16 f2bf(float f) {
  __hip_bfloat16 h = __float2bfloat16(f);
  return *reinterpret_cast<u16*>(&h);
}
static __device__ __forceinline__ u32 pack_bf(float lo, float hi) {
  return (u32)f2bf(lo) | ((u32)f2bf(hi) << 16);
}
// truncation pack: [hi.bf16 : lo.bf16] in one v_perm_b32
static __device__ __forceinline__ u32 pack_bf_trunc(float lo, float hi) {
  return __builtin_amdgcn_perm(__float_as_uint(hi), __float_as_uint(lo), 0x07060302u);
}
static __device__ __forceinline__ f32x16 zero16() {
  f32x16 z;
#pragma unroll
  for (int i = 0; i < 16; ++i) z[i] = 0.f;
  return z;
}

// async global->LDS, 16B per lane; lds base must be wave-uniform (lane*16 auto-added)
typedef __attribute__((address_space(1))) const u32* gas_t;
typedef __attribute__((address_space(3))) u32* las_t;
static __device__ __forceinline__ void g2l16(const void* g, void* l) {
  __builtin_amdgcn_global_load_lds((gas_t)g, (las_t)l, 16, 0, 0);
}

// ---------------- fused cast fp32 -> bf16 (x + 4 weights in one launch) ------
// R11 version (measured best; R12's 8-elem variant was the only delta in the
// worse 298.9 run).
__global__ __launch_bounds__(256) void cast_all(const float* __restrict__ x,
                                                const float* __restrict__ Wq,
                                                const float* __restrict__ Wk,
                                                const float* __restrict__ Wv,
                                                const float* __restrict__ Wo,
                                                u16* __restrict__ xb,
                                                u16* __restrict__ Wqb,
                                                u16* __restrict__ Wkb,
                                                u16* __restrict__ Wvb,
                                                u16* __restrict__ Wob) {
  int bid = blockIdx.x;
  const float* src;
  u16* dst;
  int off;
  if (bid < 8192) {                   // x: 8M elems
    src = x; dst = xb; off = bid;
  } else {                            // weights: 1M elems each
    int t = bid - 8192;
    int w = t >> 10;
    off   = t & 1023;
    src = w == 0 ? Wq : w == 1 ? Wk : w == 2 ? Wv : Wo;
    dst = w == 0 ? Wqb : w == 1 ? Wkb : w == 2 ? Wvb : Wob;
  }
  int i = (off * 256 + threadIdx.x) * 4;
  float4 v = *reinterpret_cast<const float4*>(src + i);
  uint2 o;
  o.x = pack_bf(v.x, v.y);
  o.y = pack_bf(v.z, v.w);
  *reinterpret_cast<uint2*>(dst + i) = o;
}

// ---------------- fused QKV GEMM: 3x [8192x1024]x[1024x1024]^T ----------------
// Verified-best structure (R3/R7/R10/R11): single-buffer 16KB LDS, 2-barrier
// K-loop, strength-reduced staging pointers, which-major XCD chunking
// (per-XCD: 2MB A-chunk resident across all 3 which-phases + 2MB W-slice
// = 4MB = L2). dbuf retested twice (R2, R8) — regresses at 128^2: the
// multi-block implicit overlap IS the pipeline (6 blocks/CU here).
__global__ __launch_bounds__(256) void gemm_qkv(const u16* __restrict__ A,
                                                const u16* __restrict__ Wq,
                                                const u16* __restrict__ Wk,
                                                const u16* __restrict__ Wv,
                                                const float* __restrict__ bq,
                                                const float* __restrict__ bk,
                                                const float* __restrict__ bv,
                                                u16* __restrict__ Qo,
                                                u16* __restrict__ Ko,
                                                u16* __restrict__ Vo) {
  const int tid  = threadIdx.x;
  const int lane = tid & 63;
  const int wave = tid >> 6;
  const int m16  = lane & 15;
  const int quad = lane >> 4;
  const int wm   = wave & 1;
  const int wn   = wave >> 1;

  // which-major bijective XCD chunking (nwg=1536, 1536%8==0)
  const int bid  = blockIdx.x;
  const int xcd  = bid & 7;
  const int j    = bid >> 3;        // [0,192)
  const int which = j >> 6;         // {0,1,2}
  const int jj   = j & 63;
  const int m0   = (xcd * 8 + (jj >> 3)) * 128;
  const int n0   = (jj & 7) * 128;

  const u16* W = which == 0 ? Wq : which == 1 ? Wk : Wv;
  const float* bias = which == 0 ? bq : which == 1 ? bk : bv;

  __shared__ __align__(16) u16 As[128 * 32];
  __shared__ __align__(16) u16 Bs[128 * 32];

  f32x4 acc[4][4];
#pragma unroll
  for (int i = 0; i < 4; ++i)
#pragma unroll
    for (int j2 = 0; j2 < 4; ++j2) acc[i][j2] = (f32x4){0.f, 0.f, 0.f, 0.f};

  // strength-reduced staging pointers: slot e holds row=e>>2, c8=(e&3)*8
  const int eA = (wave << 6) + lane;         // i=0 slot
  const int eB = 256 + (wave << 6) + lane;   // i=1 slot
  const int r0_ = eA >> 2, c0_ = (eA & 3) * 8;
  const int r1_ = eB >> 2, c1_ = (eB & 3) * 8;
  const u16* pa0 = A + (size_t)(m0 + r0_) * 1024 + c0_;
  const u16* pa1 = A + (size_t)(m0 + r1_) * 1024 + c1_;
  const u16* pw0 = W + (size_t)(n0 + r0_) * 1024 + c0_;
  const u16* pw1 = W + (size_t)(n0 + r1_) * 1024 + c1_;
  u16* lA0 = &As[((wave << 6)) * 8];
  u16* lA1 = &As[((wave << 6) + 256) * 8];
  u16* lB0 = &Bs[((wave << 6)) * 8];
  u16* lB1 = &Bs[((wave << 6) + 256) * 8];

  for (int t = 0; t < 32; ++t) {
    g2l16(pa0, lA0);
    g2l16(pw0, lB0);
    g2l16(pa1, lA1);
    g2l16(pw1, lB1);
    pa0 += 32; pa1 += 32; pw0 += 32; pw1 += 32;
    __syncthreads();   // drains stage (compiler emits vmcnt(0) before barrier)

    bf16x8 af[4], bfr[4];
#pragma unroll
    for (int mt = 0; mt < 4; ++mt)
      af[mt] = *reinterpret_cast<const bf16x8*>(&As[(wm * 64 + mt * 16 + m16) * 32 + quad * 8]);
#pragma unroll
    for (int nt = 0; nt < 4; ++nt)
      bfr[nt] = *reinterpret_cast<const bf16x8*>(&Bs[(wn * 64 + nt * 16 + m16) * 32 + quad * 8]);

#pragma unroll
    for (int mt = 0; mt < 4; ++mt)
#pragma unroll
      for (int nt = 0; nt < 4; ++nt)
        acc[mt][nt] = __builtin_amdgcn_mfma_f32_16x16x32_bf16(af[mt], bfr[nt], acc[mt][nt], 0, 0, 0);
    __syncthreads();
  }

  const float scale = which == 0 ? 0.125f * 1.44269504f : 1.0f;
  u16* ob = which == 0 ? Qo : which == 1 ? Ko : Vo;
#pragma unroll
  for (int mt = 0; mt < 4; ++mt) {
#pragma unroll
    for (int nt = 0; nt < 4; ++nt) {
      int col = n0 + wn * 64 + nt * 16 + m16;
      float bi = bias[col];
      int row0 = m0 + wm * 64 + mt * 16 + quad * 4;
      int b = row0 >> 11, s = row0 & 2047;
      int h = col >> 6,  d = col & 63;
      float v[4];
#pragma unroll
      for (int r = 0; r < 4; ++r) v[r] = (acc[mt][nt][r] + bi) * scale;
      if (which < 2) {
#pragma unroll
        for (int r = 0; r < 4; ++r)
          ob[(size_t)((b * H_ + h) * S_ + s + r) * HD_ + d] = f2bf(v[r]);
      } else {
        // V^T store: 4 consecutive s -> one 8B store
        uint2 w;
        w.x = pack_bf(v[0], v[1]);
        w.y = pack_bf(v[2], v[3]);
        *reinterpret_cast<uint2*>(&ob[(size_t)((b * H_ + h) * HD_ + d) * S_ + s]) = w;
      }
    }
  }
}

// ---------------- O-projection GEMM (fp32 out), 64x128 tile ------------------
// R13: re-tiled 128x128 -> 64m x 128n. The 512-block grid gave only 2
// blocks/CU (capacity ~6) — grid-starved latency hiding (qkv's identical
// inner loop at 6 blocks/CU runs ~20% faster per-flop). 1024 blocks -> 4
// blocks/CU, 16 waves/CU. W (2MB) is L2-resident per XCD chunk so the 2x
// re-read is free; A staged once. acc[4][2] (-32 VGPR).
// XCD chunk: per-XCD 16 m-panels(64) x 8 n-panels(128) = 2MB A + 2MB W = L2.
__global__ __launch_bounds__(256) void gemm_bt(const u16* __restrict__ A,
                                               const u16* __restrict__ W,
                                               const float* __restrict__ bias,
                                               float* __restrict__ out) {
  const int tid  = threadIdx.x;
  const int lane = tid & 63;
  const int wave = tid >> 6;
  const int m16  = lane & 15;
  const int quad = lane >> 4;

  // bijective XCD chunking: nwg=1024
  const int bid = blockIdx.x;
  const int xcd = bid & 7;
  const int j   = bid >> 3;    // [0,128)
  const int m0  = (xcd * 16 + (j >> 3)) * 64;
  const int n0  = (j & 7) * 128;

  __shared__ __align__(16) u16 As[64 * 32];    // 4KB
  __shared__ __align__(16) u16 Bs[128 * 32];   // 8KB

  f32x4 acc[4][2];
#pragma unroll
  for (int i = 0; i < 4; ++i)
#pragma unroll
    for (int j2 = 0; j2 < 2; ++j2) acc[i][j2] = (f32x4){0.f, 0.f, 0.f, 0.f};

  // staging: A = 256 slots (1/thread), W = 512 slots (2/thread)
  const int eA = (wave << 6) + lane;
  const int eB = 256 + (wave << 6) + lane;
  const int r0_ = eA >> 2, c0_ = (eA & 3) * 8;
  const int r1_ = eB >> 2, c1_ = (eB & 3) * 8;
  const u16* pa0 = A + (size_t)(m0 + r0_) * 1024 + c0_;   // A rows 0..63
  const u16* pw0 = W + (size_t)(n0 + r0_) * 1024 + c0_;   // W rows 0..63
  const u16* pw1 = W + (size_t)(n0 + r1_) * 1024 + c1_;   // W rows 64..127
  u16* lA0 = &As[((wave << 6)) * 8];
  u16* lB0 = &Bs[((wave << 6)) * 8];
  u16* lB1 = &Bs[((wave << 6) + 256) * 8];

  for (int t = 0; t < 32; ++t) {
    g2l16(pa0, lA0);
    g2l16(pw0, lB0);
    g2l16(pw1, lB1);
    pa0 += 32; pw0 += 32; pw1 += 32;
    __syncthreads();

    bf16x8 af[4], bfr[2];
#pragma unroll
    for (int mt = 0; mt < 4; ++mt)
      af[mt] = *reinterpret_cast<const bf16x8*>(&As[(mt * 16 + m16) * 32 + quad * 8]);
#pragma unroll
    for (int nt = 0; nt < 2; ++nt)
      bfr[nt] = *reinterpret_cast<const bf16x8*>(&Bs[(wave * 32 + nt * 16 + m16) * 32 + quad * 8]);

#pragma unroll
    for (int mt = 0; mt < 4; ++mt)
#pragma unroll
      for (int nt = 0; nt < 2; ++nt)
        acc[mt][nt] = __builtin_amdgcn_mfma_f32_16x16x32_bf16(af[mt], bfr[nt], acc[mt][nt], 0, 0, 0);
    __syncthreads();
  }

#pragma unroll
  for (int mt = 0; mt < 4; ++mt) {
#pragma unroll
    for (int nt = 0; nt < 2; ++nt) {
      int col = n0 + wave * 32 + nt * 16 + m16;
      float bi = bias[col];
#pragma unroll
      for (int r = 0; r < 4; ++r) {
        int row = m0 + mt * 16 + quad * 4 + r;
        out[(size_t)row * 1024 + col] = acc[mt][nt][r] + bi;
      }
    }
  }
}

// ---------------- flash attention, 32x32 MFMA ----------------
// Best measured attn (83.8-85.8us across R9-R12, stable): R1 indexing (no
// XCD swizzle — duration-neutral-to-negative despite FETCH 139->25MB),
// plain epilogue stores (nt-stores caused 4-5x write amplification),
// strength-reduced prefetch pointers, dbuf 1-barrier loop, permlane32_swap,
// setprio, VALU lsum denominator.
__global__ __launch_bounds__(256, 4) void attn_kernel(const u16* __restrict__ Q,
                                                      const u16* __restrict__ K,
                                                      const u16* __restrict__ Vt,
                                                      u16* __restrict__ out) {
  const int tid  = threadIdx.x;
  const int lane = tid & 63;
  const int wave = tid >> 6;
  const int r32  = lane & 31;
  const int h32  = lane >> 5;
  const int bh   = blockIdx.y;
  const int q0   = blockIdx.x * 128 + wave * 32;

  __shared__ __align__(16) u16 Ks[2][64 * 72];   // [buf][key][d], stride 72
  __shared__ __align__(16) u16 Vs[2][64 * 72];   // [buf][d][key]

  const u16* kbase = K  + (size_t)bh * S_ * HD_;
  const u16* vbase = Vt + (size_t)bh * HD_ * S_;
  const int e  = tid;          // staging slot 0
  const int e2 = tid + 256;    // staging slot 1
  const int row_a = e >> 3,  c8_a = (e & 7) * 8;
  const int row_b = e2 >> 3, c8_b = (e2 & 7) * 8;

  // Q B-frags: B[k=d][n=qrow]
  bf16x8 qf[4];
  {
    const u16* qbase = Q + (size_t)(bh * S_ + q0 + r32) * HD_ + h32 * 8;
#pragma unroll
    for (int dc = 0; dc < 4; ++dc)
      qf[dc] = *reinterpret_cast<const bf16x8*>(qbase + dc * 16);
  }

  f32x16 acc[2];   // O^T accum [dt], row=d col=qrow
#pragma unroll
  for (int dt = 0; dt < 2; ++dt) acc[dt] = zero16();
  float lsum = 0.f;

  // strength-reduced prefetch pointers
  const u16* pkp0 = kbase + (size_t)row_a * HD_ + c8_a;
  const u16* pkp1 = kbase + (size_t)row_b * HD_ + c8_b;
  const u16* pvp0 = vbase + (size_t)row_a * S_ + c8_a;
  const u16* pvp1 = vbase + (size_t)row_b * S_ + c8_b;

  // prefetch tile 0
  uint4 kr0 = *reinterpret_cast<const uint4*>(pkp0);
  uint4 kr1 = *reinterpret_cast<const uint4*>(pkp1);
  uint4 vr0 = *reinterpret_cast<const uint4*>(pvp0);
  uint4 vr1 = *reinterpret_cast<const uint4*>(pvp1);

  const int NT = S_ / 64;
  for (int kt = 0; kt < NT; ++kt) {
    u16* ks = Ks[kt & 1];
    u16* vs = Vs[kt & 1];
    // write prefetched tile to LDS (current buffer)
    *reinterpret_cast<uint4*>(&ks[row_a * 72 + c8_a]) = kr0;
    *reinterpret_cast<uint4*>(&ks[row_b * 72 + c8_b]) = kr1;
    *reinterpret_cast<uint4*>(&vs[row_a * 72 + c8_a]) = vr0;
    *reinterpret_cast<uint4*>(&vs[row_b * 72 + c8_b]) = vr1;
    __syncthreads();

    // issue next tile's loads (last iter reads slightly OOB into adjacent
    // ws regions; values discarded)
    pkp0 += 64 * HD_; pkp1 += 64 * HD_; pvp0 += 64; pvp1 += 64;
    kr0 = *reinterpret_cast<const uint4*>(pkp0);
    kr1 = *reinterpret_cast<const uint4*>(pkp1);
    vr0 = *reinterpret_cast<const uint4*>(pvp0);
    vr1 = *reinterpret_cast<const uint4*>(pvp1);

    // S^T tiles (two 32-key tiles x 32 qrows)
    f32x16 sc[2];
    __builtin_amdgcn_s_setprio(1);
#pragma unroll
    for (int nt = 0; nt < 2; ++nt) {
      sc[nt] = zero16();
#pragma unroll
      for (int dc = 0; dc < 4; ++dc) {
        bf16x8 kf = *reinterpret_cast<const bf16x8*>(&ks[(nt * 32 + r32) * 72 + dc * 16 + h32 * 8]);
        sc[nt] = __builtin_amdgcn_mfma_f32_32x32x16_bf16(kf, qf[dc], sc[nt], 0, 0, 0);
      }
    }
    __builtin_amdgcn_s_setprio(0);

    // fixed-max softmax: p = 2^score; truncation-pack pairs to bf16x2
    u32 pk[2][8];
    float ps0 = 0.f, ps1 = 0.f;
#pragma unroll
    for (int nt = 0; nt < 2; ++nt)
#pragma unroll
      for (int i = 0; i < 8; ++i) {
        float p0 = __builtin_amdgcn_exp2f(sc[nt][2 * i]);
        float p1 = __builtin_amdgcn_exp2f(sc[nt][2 * i + 1]);
        ps0 += p0;
        ps1 += p1;
        pk[nt][i] = pack_bf_trunc(p0, p1);
      }
    lsum += ps0 + ps1;

    // PV: assemble P^T B-frag per 16-key chunk via permlane32_swap,
    // accumulate O^T = V^T . P^T
    __builtin_amdgcn_s_setprio(1);
#pragma unroll
    for (int nt = 0; nt < 2; ++nt) {
#pragma unroll
      for (int kc2 = 0; kc2 < 2; ++kc2) {
        u32x2 r0 = __builtin_amdgcn_permlane32_swap(pk[nt][4 * kc2 + 0], pk[nt][4 * kc2 + 2], false, false);
        u32x2 r1 = __builtin_amdgcn_permlane32_swap(pk[nt][4 * kc2 + 1], pk[nt][4 * kc2 + 3], false, false);
        u32x4 bw;
        bw[0] = r0[0];
        bw[1] = r1[0];
        bw[2] = r0[1];
        bw[3] = r1[1];
        bf16x8 pfrag = *reinterpret_cast<bf16x8*>(&bw);
        const int kc = nt * 2 + kc2;
#pragma unroll
        for (int dt = 0; dt < 2; ++dt) {
          bf16x8 vf = *reinterpret_cast<const bf16x8*>(&vs[(dt * 32 + r32) * 72 + kc * 16 + h32 * 8]);
          acc[dt] = __builtin_amdgcn_mfma_f32_32x32x16_bf16(vf, pfrag, acc[dt], 0, 0, 0);
        }
      }
    }
    __builtin_amdgcn_s_setprio(0);
    // no second barrier: double-buffered LDS makes next-iter writes safe
  }

  // epilogue: O^T regs -> out[b, s, h*64+d]; d = dt*32 + 8g + 4*h32 + (0..3)
  const int b = bh >> 4, hh = bh & 15;
  float lt  = lsum + __shfl_xor(lsum, 32);
  float inv = 1.f / lt;
  int srow = q0 + r32;
  u16* orow = out + (size_t)(b * S_ + srow) * D_ + hh * HD_;
#pragma unroll
  for (int dt = 0; dt < 2; ++dt) {
#pragma unroll
    for (int g = 0; g < 4; ++g) {
      uint2 w;
      w.x = pack_bf(acc[dt][4 * g + 0] * inv, acc[dt][4 * g + 1] * inv);
      w.y = pack_bf(acc[dt][4 * g + 2] * inv, acc[dt][4 * g + 3] * inv);
      *reinterpret_cast<uint2*>(orow + dt * 32 + 8 * g + 4 * h32) = w;
    }
  }
}

// ---------------- layernorm: wave-per-row, no LDS, no barrier ----------------
// One 64-lane wave owns a full 1024-col row (16 elems/lane as 4x float4);
// reduction is pure shfl_xor. No __syncthreads, no LDS round-trip.
__global__ __launch_bounds__(256) void ln_kernel(const float* __restrict__ X,
                                                 const float* __restrict__ w,
                                                 const float* __restrict__ b,
                                                 float* __restrict__ out) {
  const int wave = threadIdx.x >> 6;
  const int lane = threadIdx.x & 63;
  const int row  = blockIdx.x * 4 + wave;
  const float* x = X + (size_t)row * 1024;

  float4 v[4];
  float s = 0.f, s2 = 0.f;
#pragma unroll
  for (int i = 0; i < 4; ++i) {
    v[i] = *reinterpret_cast<const float4*>(x + lane * 4 + i * 256);
    s  += (v[i].x + v[i].y) + (v[i].z + v[i].w);
    s2 += (v[i].x * v[i].x + v[i].y * v[i].y) + (v[i].z * v[i].z + v[i].w * v[i].w);
  }
#pragma unroll
  for (int off = 32; off; off >>= 1) {
    s  += __shfl_xor(s, off);
    s2 += __shfl_xor(s2, off);
  }
  float mu  = s * (1.f / 1024.f);
  float var = s2 * (1.f / 1024.f) - mu * mu;
  float inv = rsqrtf(var + 1e-5f);
  float* orow = out + (size_t)row * 1024;
#pragma unroll
  for (int i = 0; i < 4; ++i) {
    const int c = lane * 4 + i * 256;
    float4 wv = *reinterpret_cast<const float4*>(w + c);
    float4 bv = *reinterpret_cast<const float4*>(b + c);
    float4 o;
    o.x = (v[i].x - mu) * inv * wv.x + bv.x;
    o.y = (v[i].y - mu) * inv * wv.y + bv.y;
    o.z = (v[i].z - mu) * inv * wv.z + bv.z;
    o.w = (v[i].w - mu) * inv * wv.w + bv.w;
    *reinterpret_cast<float4*>(orow + c) = o;
  }
}

// ---------------- launch ----------------
extern "C" void kernel_launch(void* const* d_in, const int* in_sizes, int n_in,
                              void* d_out, int out_size, void* d_ws, size_t ws_size,
                              hipStream_t stream) {
  const float* x   = (const float*)d_in[0];
  const float* Wq  = (const float*)d_in[1];
  const float* bq  = (const float*)d_in[2];
  const float* Wk  = (const float*)d_in[3];
  const float* bk  = (const float*)d_in[4];
  const float* Wv  = (const float*)d_in[5];
  const float* bv  = (const float*)d_in[6];
  const float* Wo  = (const float*)d_in[7];
  const float* bo  = (const float*)d_in[8];
  const float* lnw = (const float*)d_in[9];
  const float* lnb = (const float*)d_in[10];

  const size_t MB = 1024ull * 1024ull;
  char* ws = (char*)d_ws;
  u16* xb  = (u16*)(ws + 0);        // 16 MB; later reused as attention output
  u16* Qb  = (u16*)(ws + 16 * MB);  // 16 MB
  u16* Kb  = (u16*)(ws + 32 * MB);  // 16 MB
  u16* Vtb = (u16*)(ws + 48 * MB);  // 16 MB
  u16* Wqb = (u16*)(ws + 64 * MB);  // 2 MB each
  u16* Wkb = (u16*)(ws + 66 * MB);
  u16* Wvb = (u16*)(ws + 68 * MB);
  u16* Wob = (u16*)(ws + 70 * MB);
  float* Of = (float*)(ws + 16 * MB); // 32 MB fp32, overlaps Qb/Kb (dead after attn)

  cast_all<<<8192 + 4096, 256, 0, stream>>>(x, Wq, Wk, Wv, Wo, xb, Wqb, Wkb, Wvb, Wob);

  gemm_qkv<<<(M_ / 128) * 3 * (D_ / 128), 256, 0, stream>>>(
      xb, Wqb, Wkb, Wvb, bq, bk, bv, Qb, Kb, Vtb);

  attn_kernel<<<dim3(S_ / 128, B_ * H_), 256, 0, stream>>>(Qb, Kb, Vtb, xb);

  gemm_bt<<<(M_ / 64) * (D_ / 128), 256, 0, stream>>>(xb, Wob, bo, Of);

  ln_kernel<<<M_ / 4, 256, 0, stream>>>(Of, lnw, lnb, (float*)d_out);
}